// Round 4
// baseline (124.470 us; speedup 1.0000x reference)
//
#include <hip/hip_runtime.h>
#include <hip/hip_bf16.h>
#include <math.h>

#define N_Q   512
#define M_ALL 2048
#define CHN   256
#define TOPK  6
#define NREF  10
#define INV_C (1.0f / 256.0f)
#define NBLK  256

// ws layout: u32[0..2) barrier counters (memset to 0 each launch).
// float offsets:
//   [WS_AW_F   ..) aw   : micro_all*(w-1/C) bf16 [M][C]   (1 MB)
//   [WS_BIAS_F ..) bias : sum_c a*aw f32 [M]               (8 KB)
//   [WS_BMIC_F ..) bmic : micro bf16 [N][C]                (256 KB)
//   [WS_LOGIT_F..) logits f32 [N][M]                       (4 MB)
#define WS_AW_F    4096
#define WS_BIAS_F  (WS_AW_F + (M_ALL * CHN) / 2)
#define WS_BMIC_F  (WS_BIAS_F + M_ALL)
#define WS_LOGIT_F (WS_BMIC_F + (N_Q * CHN) / 2)

typedef __bf16 bf16x8 __attribute__((ext_vector_type(8)));
typedef float  f32x4  __attribute__((ext_vector_type(4)));

static __device__ __forceinline__ unsigned short bfbits(float x) {
    __bf16 h = (__bf16)x;
    unsigned short u;
    __builtin_memcpy(&u, &h, 2);
    return u;
}

// sortable u32 key with 11-bit m-index embedded in the low (dropped) mantissa bits
static __device__ __forceinline__ unsigned key_of(float f, int m) {
    unsigned u = __float_as_uint(f);
    u = (u & 0x80000000u) ? ~u : (u | 0x80000000u);
    return (u & 0xFFFFF800u) | (unsigned)m;
}

// device-scope grid barrier: counter + spin. Safe: all 256 blocks co-resident
// (1024 waves total vs 8192 capacity; ~130 VGPR -> >=3 blocks/CU possible).
static __device__ __forceinline__ void grid_sync(unsigned* bar) {
    __syncthreads();
    if (threadIdx.x == 0) {
        __threadfence();                                   // release my writes
        const unsigned arrived = atomicAdd(bar, 1u) + 1u;  // device scope
        if (arrived < NBLK) {
            while (__hip_atomic_load(bar, __ATOMIC_RELAXED,
                                     __HIP_MEMORY_SCOPE_AGENT) < NBLK)
                __builtin_amdgcn_s_sleep(2);
        }
        __threadfence();                                   // acquire remote writes
    }
    __syncthreads();
}

// ===================== single fused kernel =====================
#define BLOCK 256
#define WAVES 4
#define MPT   (M_ALL / BLOCK)     // 8 logits per thread in topk phase
#define WTOP  8
#define NCAND (WAVES * WTOP)      // 32

__global__ __launch_bounds__(256) void gcn_fused(
    const float* __restrict__ micro_all,
    const float* __restrict__ micro,
    const float* __restrict__ fc_w,
    const float* __restrict__ label,
    const float* __restrict__ label_all,
    unsigned short* __restrict__ aw,
    float* __restrict__ bias,
    unsigned short* __restrict__ bmic,
    float* __restrict__ logits,
    float* __restrict__ out,
    unsigned* __restrict__ bar)
{
    __shared__ unsigned s_keys[NCAND];
    __shared__ unsigned s_top[NREF];
    __shared__ float    s_ex[NREF];

    const int b    = blockIdx.x;
    const int t    = threadIdx.x;
    const int w    = t >> 6;
    const int lane = t & 63;
    const int l15  = lane & 15;
    const int quad = lane >> 4;

    // ---------------- phase A: bf16 prep + bias ----------------
    {
        float4 wv = *(const float4*)(fc_w + lane * 4);
        wv.x -= INV_C; wv.y -= INV_C; wv.z -= INV_C; wv.w -= INV_C;

        #pragma unroll
        for (int r2 = 0; r2 < 2; ++r2) {
            const int row = b * 8 + w * 2 + r2;
            const float4 a = *(const float4*)(micro_all + (size_t)row * CHN + lane * 4);
            const float sx = a.x * wv.x, sy = a.y * wv.y, sz = a.z * wv.z, sw = a.w * wv.w;
            ushort4 pk;
            pk.x = bfbits(sx); pk.y = bfbits(sy); pk.z = bfbits(sz); pk.w = bfbits(sw);
            *(ushort4*)(aw + (size_t)row * CHN + lane * 4) = pk;

            float p = a.x * sx + a.y * sy + a.z * sz + a.w * sw;
            #pragma unroll
            for (int mask = 32; mask >= 1; mask >>= 1)
                p += __shfl_xor(p, mask, 64);
            if (lane == 0) bias[row] = p;
        }

        if (w < 2) {
            const int row = b * 2 + w;
            const float4 a = *(const float4*)(micro + (size_t)row * CHN + lane * 4);
            ushort4 pk;
            pk.x = bfbits(a.x); pk.y = bfbits(a.y); pk.z = bfbits(a.z); pk.w = bfbits(a.w);
            *(ushort4*)(bmic + (size_t)row * CHN + lane * 4) = pk;
        }

        if (b == 0 && t == 0) out[N_Q * CHN] = 1e-4f;  // loss seed
    }
    grid_sync(bar + 0);

    // ---------------- phase B: MFMA gemm (2 tiles of 64m x 32n) ----------------
    {
        const int n0  = ((2 * b) >> 5) * 32;   // same n-tile for both of this block's tiles
        const int nt  = w & 1;
        const int mtp = w >> 1;

        // hoist B-fragments (bf16, shared by both tiles)
        const unsigned short* brow = bmic + (size_t)(n0 + nt * 16 + l15) * CHN;
        bf16x8 bq[8];
        #pragma unroll
        for (int ks = 0; ks < 8; ++ks)
            bq[ks] = *(const bf16x8*)(brow + ks * 32 + quad * 8);

        #pragma unroll
        for (int ti = 0; ti < 2; ++ti) {
            const int tau = 2 * b + ti;
            const int m0  = (tau & 31) * 64;

            const unsigned short* arow0 = aw + (size_t)(m0 + mtp * 32 + l15) * CHN;
            const unsigned short* arow1 = arow0 + 16 * CHN;

            f32x4 acc0 = {0.f, 0.f, 0.f, 0.f};
            f32x4 acc1 = {0.f, 0.f, 0.f, 0.f};
            #pragma unroll
            for (int ks = 0; ks < 8; ++ks) {
                const int k0 = ks * 32 + quad * 8;
                const bf16x8 b0 = *(const bf16x8*)(arow0 + k0);
                const bf16x8 b1 = *(const bf16x8*)(arow1 + k0);
                acc0 = __builtin_amdgcn_mfma_f32_16x16x32_bf16(bq[ks], b0, acc0, 0, 0, 0);
                acc1 = __builtin_amdgcn_mfma_f32_16x16x32_bf16(bq[ks], b1, acc1, 0, 0, 0);
            }

            const float bias0 = bias[m0 + mtp * 32 + l15];
            const float bias1 = bias[m0 + mtp * 32 + 16 + l15];
            #pragma unroll
            for (int reg = 0; reg < 4; ++reg) {
                const int n = n0 + nt * 16 + quad * 4 + reg;
                logits[(size_t)n * M_ALL + m0 + mtp * 32 + l15]      = bias0 - 2.f * acc0[reg];
                logits[(size_t)n * M_ALL + m0 + mtp * 32 + 16 + l15] = bias1 - 2.f * acc1[reg];
            }
        }
    }
    grid_sync(bar + 1);

    // ---------------- phase C: topk + exact refine + epilogue (2 n-rows) ----------------
    // per-lane channel slice for the exact recompute
    float4 w4 = *(const float4*)(fc_w + lane * 4);
    w4.x -= INV_C; w4.y -= INV_C; w4.z -= INV_C; w4.w -= INV_C;

    for (int it = 0; it < 2; ++it) {
        const int n = 2 * b + it;
        __syncthreads();   // guard shared reuse across iterations

        const float4 b4 = *(const float4*)(micro + (size_t)n * CHN + lane * 4);

        // load + pack 8 contiguous logits per thread (m = t*8+j, fits 11 bits)
        unsigned k8[MPT];
        {
            const float4 v0 = *(const float4*)(logits + (size_t)n * M_ALL + t * 8);
            const float4 v1 = *(const float4*)(logits + (size_t)n * M_ALL + t * 8 + 4);
            const int mb = t * 8;
            k8[0] = key_of(v0.x, mb + 0);
            k8[1] = key_of(v0.y, mb + 1);
            k8[2] = key_of(v0.z, mb + 2);
            k8[3] = key_of(v0.w, mb + 3);
            k8[4] = key_of(v1.x, mb + 4);
            k8[5] = key_of(v1.y, mb + 5);
            k8[6] = key_of(v1.z, mb + 6);
            k8[7] = key_of(v1.w, mb + 7);
        }

        // per-wave exhaustive top-8 via packed umax butterflies
        #pragma unroll
        for (int k = 0; k < WTOP; ++k) {
            unsigned best = k8[0];
            #pragma unroll
            for (int j = 1; j < MPT; ++j) best = (k8[j] > best) ? k8[j] : best;
            #pragma unroll
            for (int mask = 32; mask > 0; mask >>= 1) {
                const unsigned ov = __shfl_xor(best, mask, 64);
                best = (ov > best) ? ov : best;
            }
            if (lane == 0) s_keys[w * WTOP + k] = best;
            #pragma unroll
            for (int j = 0; j < MPT; ++j)
                k8[j] = (k8[j] == best) ? 0u : k8[j];
        }
        __syncthreads();

        // top-10 of the 32 candidates: 32-lane bitonic sort (descending)
        {
            unsigned v = s_keys[lane & 31];
            #pragma unroll
            for (int k = 2; k <= 32; k <<= 1) {
                #pragma unroll
                for (int j = k >> 1; j >= 1; j >>= 1) {
                    const unsigned pv = __shfl_xor(v, j, 64);
                    const unsigned mx = (v > pv) ? v : pv;
                    const unsigned mn = (v > pv) ? pv : v;
                    const bool up    = ((lane & k) == 0);
                    const bool lower = ((lane & j) == 0);
                    v = (up == lower) ? mx : mn;
                }
            }
            if (w == 0 && lane < NREF) s_top[lane] = v;
        }
        __syncthreads();

        // exact fp32 recompute of the 10 candidates
        for (int c = w; c < NREF; c += WAVES) {
            const int m = (int)(s_top[c] & 0x7FFu);
            const float4 a = *(const float4*)(micro_all + (size_t)m * CHN + lane * 4);
            const float dx = a.x - b4.x;
            const float dy = a.y - b4.y;
            const float dz = a.z - b4.z;
            const float dw = a.w - b4.w;
            float acc = dx * dx * w4.x + dy * dy * w4.y + dz * dz * w4.z + dw * dw * w4.w;
            #pragma unroll
            for (int mask = 32; mask >= 1; mask >>= 1)
                acc += __shfl_xor(acc, mask, 64);
            if (lane == 0) s_ex[c] = acc;
        }
        __syncthreads();

        // exact top-6 of 10 (index-tracked, identical in every thread)
        float top_val[TOPK];
        int   top_idx[TOPK];
        unsigned rtk = 0u;
        #pragma unroll
        for (int k = 0; k < TOPK; ++k) {
            float best = -INFINITY;
            int   bi   = 0;
            #pragma unroll
            for (int c = 0; c < NREF; ++c) {
                const bool avail = ((rtk >> c) & 1u) == 0u;
                const float cv = s_ex[c];
                if (avail && cv > best) { best = cv; bi = c; }
            }
            top_val[k] = best;
            top_idx[k] = (int)(s_top[bi] & 0x7FFu);
            rtk |= 1u << bi;
        }

        // softmax over exact top-6
        const float mx = top_val[0];
        float e[TOPK];
        float esum = 0.0f;
        #pragma unroll
        for (int k = 0; k < TOPK; ++k) { e[k] = __expf(top_val[k] - mx); esum += e[k]; }
        const float inv = 1.0f / esum;

        float outv = micro[(size_t)n * CHN + t];
        #pragma unroll
        for (int k = 0; k < TOPK; ++k)
            outv += (e[k] * inv) * micro_all[(size_t)top_idx[k] * CHN + t];
        out[(size_t)n * CHN + t] = outv;

        if (t == 0) {
            const float lab = label[n];
            float l = 0.0f;
            #pragma unroll
            for (int k = 0; k < TOPK; ++k)
                l += (e[k] * inv) * fabsf(label_all[top_idx[k]] - lab);
            atomicAdd(out + N_Q * CHN, l * (1.0f / (float)N_Q));
        }
    }
}

extern "C" void kernel_launch(void* const* d_in, const int* in_sizes, int n_in,
                              void* d_out, int out_size, void* d_ws, size_t ws_size,
                              hipStream_t stream) {
    const float* micro     = (const float*)d_in[0];
    const float* label     = (const float*)d_in[1];
    const float* micro_all = (const float*)d_in[2];
    const float* label_all = (const float*)d_in[3];
    const float* fc_w      = (const float*)d_in[4];
    float* out  = (float*)d_out;
    float* ws   = (float*)d_ws;

    unsigned*       bar    = (unsigned*)ws;
    unsigned short* aw     = (unsigned short*)(ws + WS_AW_F);
    float*          bias   = ws + WS_BIAS_F;
    unsigned short* bmic   = (unsigned short*)(ws + WS_BMIC_F);
    float*          logits = ws + WS_LOGIT_F;

    hipMemsetAsync(bar, 0, 2 * sizeof(unsigned), stream);
    gcn_fused<<<NBLK, BLOCK, 0, stream>>>(micro_all, micro, fc_w, label, label_all,
                                          aw, bias, bmic, logits, out, bar);
}

// Round 5
// 91.228 us; speedup vs baseline: 1.3644x; 1.3644x over previous
//
#include <hip/hip_runtime.h>
#include <hip/hip_bf16.h>
#include <math.h>

#define N_Q   512
#define M_ALL 2048
#define CHN   256
#define TOPK  6
#define NREF  10
#define INV_C (1.0f / 256.0f)

// ws layout (float offsets): [4096..) logits f32 [N][M] (4 MB)
#define WS_LOGIT_F 4096

typedef __bf16 bf16x8 __attribute__((ext_vector_type(8)));
typedef float  f32x4  __attribute__((ext_vector_type(4)));

// sortable u32 key with 11-bit m-index embedded in the low (dropped) mantissa bits
static __device__ __forceinline__ unsigned key_of(float f, int m) {
    unsigned u = __float_as_uint(f);
    u = (u & 0x80000000u) ? ~u : (u | 0x80000000u);
    return (u & 0xFFFFF800u) | (unsigned)m;
}

static __device__ __forceinline__ bf16x8 cvt8(float4 lo, float4 hi) {
    bf16x8 r;
    r[0] = (__bf16)lo.x; r[1] = (__bf16)lo.y; r[2] = (__bf16)lo.z; r[3] = (__bf16)lo.w;
    r[4] = (__bf16)hi.x; r[5] = (__bf16)hi.y; r[6] = (__bf16)hi.z; r[7] = (__bf16)hi.w;
    return r;
}

// ============ kernel 1: MFMA GEMM, register-resident convert + bias ============
// 512 blocks x 256 thr (2/CU, 8 waves). No LDS, no barriers, no prep pass.
// Lane (l15,quad) owns A-rows m0+mtp*32+l15(+16) over channels ks*32+quad*8;
// bias = sum_c a*(a*(w-1/C)) accumulates in-register and quad-reduces via
// shfl_xor(16,32) into exactly the lanes that write that m-column.
#define BM 64
#define BN 32

__global__ __launch_bounds__(256) void gcn_gemm(
    const float* __restrict__ micro_all,
    const float* __restrict__ micro,
    const float* __restrict__ fc_w,
    float* __restrict__ logits,
    float* __restrict__ out)
{
    const int t    = threadIdx.x;
    const int w    = t >> 6;
    const int l15  = t & 15;
    const int quad = (t >> 4) & 3;
    const int m0   = blockIdx.x * BM;
    const int n0   = blockIdx.y * BN;

    if (blockIdx.x == 0 && blockIdx.y == 0 && t == 0)
        out[N_Q * CHN] = 1e-4f;   // loss accumulator seed

    const int nt  = w & 1;   // n-tile (16 rows)
    const int mtp = w >> 1;  // m-half (32 rows)

    const float* brow  = micro     + (size_t)(n0 + nt * 16 + l15) * CHN;
    const float* arow0 = micro_all + (size_t)(m0 + mtp * 32 + l15) * CHN;
    const float* arow1 = arow0 + 16 * CHN;

    f32x4 acc0 = {0.f, 0.f, 0.f, 0.f};
    f32x4 acc1 = {0.f, 0.f, 0.f, 0.f};
    float p0 = 0.0f, p1 = 0.0f;

    #pragma unroll
    for (int ks = 0; ks < 8; ++ks) {
        const int k0 = ks * 32 + quad * 8;

        float4 w0 = *(const float4*)(fc_w + k0);
        float4 w1 = *(const float4*)(fc_w + k0 + 4);
        w0.x -= INV_C; w0.y -= INV_C; w0.z -= INV_C; w0.w -= INV_C;
        w1.x -= INV_C; w1.y -= INV_C; w1.z -= INV_C; w1.w -= INV_C;

        const float4 b0 = *(const float4*)(brow + k0);
        const float4 b1 = *(const float4*)(brow + k0 + 4);
        const bf16x8 bfr = cvt8(b0, b1);

        // A-row 0: s = a*(w-1/C) fp32, fragment = bf16(s), bias += a*s
        {
            const float4 a0 = *(const float4*)(arow0 + k0);
            const float4 a1 = *(const float4*)(arow0 + k0 + 4);
            float4 s0, s1;
            s0.x = a0.x * w0.x; s0.y = a0.y * w0.y; s0.z = a0.z * w0.z; s0.w = a0.w * w0.w;
            s1.x = a1.x * w1.x; s1.y = a1.y * w1.y; s1.z = a1.z * w1.z; s1.w = a1.w * w1.w;
            p0 += a0.x * s0.x + a0.y * s0.y + a0.z * s0.z + a0.w * s0.w
                + a1.x * s1.x + a1.y * s1.y + a1.z * s1.z + a1.w * s1.w;
            acc0 = __builtin_amdgcn_mfma_f32_16x16x32_bf16(bfr, cvt8(s0, s1), acc0, 0, 0, 0);
        }
        // A-row 1 (+16)
        {
            const float4 a0 = *(const float4*)(arow1 + k0);
            const float4 a1 = *(const float4*)(arow1 + k0 + 4);
            float4 s0, s1;
            s0.x = a0.x * w0.x; s0.y = a0.y * w0.y; s0.z = a0.z * w0.z; s0.w = a0.w * w0.w;
            s1.x = a1.x * w1.x; s1.y = a1.y * w1.y; s1.z = a1.z * w1.z; s1.w = a1.w * w1.w;
            p1 += a0.x * s0.x + a0.y * s0.y + a0.z * s0.z + a0.w * s0.w
                + a1.x * s1.x + a1.y * s1.y + a1.z * s1.z + a1.w * s1.w;
            acc1 = __builtin_amdgcn_mfma_f32_16x16x32_bf16(bfr, cvt8(s0, s1), acc1, 0, 0, 0);
        }
    }

    // quad-reduce bias: lanes {l15, l15+16, l15+32, l15+48} sum their 64-ch partials
    p0 += __shfl_xor(p0, 16, 64); p0 += __shfl_xor(p0, 32, 64);
    p1 += __shfl_xor(p1, 16, 64); p1 += __shfl_xor(p1, 32, 64);

    #pragma unroll
    for (int reg = 0; reg < 4; ++reg) {
        const int n = n0 + nt * 16 + quad * 4 + reg;
        logits[(size_t)n * M_ALL + m0 + mtp * 32 + l15]      = p0 - 2.f * acc0[reg];
        logits[(size_t)n * M_ALL + m0 + mtp * 32 + 16 + l15] = p1 - 2.f * acc1[reg];
    }
}

// ============ kernel 2: packed-key top-k + exact refine + fused loss ============
#define BLOCK 256
#define WAVES (BLOCK / 64)
#define MPT   (M_ALL / BLOCK)
#define WTOP  8                   // per-wave exhaustive top-8 (packed keys)
#define NCAND (WAVES * WTOP)      // 32

__global__ __launch_bounds__(BLOCK) void gcn_topk(
    const float* __restrict__ logits,
    const float* __restrict__ micro,
    const float* __restrict__ label,
    const float* __restrict__ micro_all,
    const float* __restrict__ label_all,
    const float* __restrict__ fc_w,
    float* __restrict__ out)
{
    __shared__ unsigned s_keys[NCAND];
    __shared__ unsigned s_top[NREF];
    __shared__ float    s_ex[NREF];

    const int n    = blockIdx.x;
    const int t    = threadIdx.x;
    const int wave = t >> 6;
    const int lane = t & 63;

    // per-lane channel slice for the exact recompute (independent of logits)
    const float4 b4 = *(const float4*)(micro + (size_t)n * CHN + lane * 4);
    float4 w4 = *(const float4*)(fc_w + lane * 4);
    w4.x -= INV_C; w4.y -= INV_C; w4.z -= INV_C; w4.w -= INV_C;

    // contiguous per-thread slice: two float4 loads; m = t*8+j fits 11 bits
    unsigned k8[MPT];
    {
        const float4 v0 = *(const float4*)(logits + (size_t)n * M_ALL + t * 8);
        const float4 v1 = *(const float4*)(logits + (size_t)n * M_ALL + t * 8 + 4);
        const int mb = t * 8;
        k8[0] = key_of(v0.x, mb + 0);
        k8[1] = key_of(v0.y, mb + 1);
        k8[2] = key_of(v0.z, mb + 2);
        k8[3] = key_of(v0.w, mb + 3);
        k8[4] = key_of(v1.x, mb + 4);
        k8[5] = key_of(v1.y, mb + 5);
        k8[6] = key_of(v1.z, mb + 6);
        k8[7] = key_of(v1.w, mb + 7);
    }

    // ---- per-wave exhaustive top-8 via packed umax butterflies ----
    #pragma unroll
    for (int k = 0; k < WTOP; ++k) {
        unsigned best = k8[0];
        #pragma unroll
        for (int j = 1; j < MPT; ++j) best = (k8[j] > best) ? k8[j] : best;
        #pragma unroll
        for (int mask = 32; mask > 0; mask >>= 1) {
            const unsigned ov = __shfl_xor(best, mask, 64);
            best = (ov > best) ? ov : best;
        }
        if (lane == 0) s_keys[wave * WTOP + k] = best;
        #pragma unroll
        for (int j = 0; j < MPT; ++j)
            k8[j] = (k8[j] == best) ? 0u : k8[j];
    }
    __syncthreads();

    // ---- top-10 of the 32 candidates: 32-lane bitonic sort (descending) ----
    {
        unsigned v = s_keys[lane & 31];
        #pragma unroll
        for (int k = 2; k <= 32; k <<= 1) {
            #pragma unroll
            for (int j = k >> 1; j >= 1; j >>= 1) {
                const unsigned pv = __shfl_xor(v, j, 64);
                const unsigned mx = (v > pv) ? v : pv;
                const unsigned mn = (v > pv) ? pv : v;
                const bool up    = ((lane & k) == 0);
                const bool lower = ((lane & j) == 0);
                v = (up == lower) ? mx : mn;   // descending in "up" blocks
            }
        }
        if (wave == 0 && lane < NREF) s_top[lane] = v;  // lanes 0..9 descending
    }
    __syncthreads();

    // ---- exact fp32 recompute of the 10 candidates ----
    for (int c = wave; c < NREF; c += WAVES) {
        const int m = (int)(s_top[c] & 0x7FFu);
        const float4 a = *(const float4*)(micro_all + (size_t)m * CHN + lane * 4);
        const float dx = a.x - b4.x;
        const float dy = a.y - b4.y;
        const float dz = a.z - b4.z;
        const float dw = a.w - b4.w;
        float acc = dx * dx * w4.x + dy * dy * w4.y + dz * dz * w4.z + dw * dw * w4.w;
        #pragma unroll
        for (int mask = 32; mask >= 1; mask >>= 1)
            acc += __shfl_xor(acc, mask, 64);
        if (lane == 0) s_ex[c] = acc;
    }
    __syncthreads();

    // ---- exact top-6 of 10 (fp32, index-tracked, every thread identical) ----
    float top_val[TOPK];
    int   top_idx[TOPK];
    unsigned rtk = 0u;
    #pragma unroll
    for (int k = 0; k < TOPK; ++k) {
        float best = -INFINITY;
        int   bi   = 0;
        #pragma unroll
        for (int c = 0; c < NREF; ++c) {
            const bool avail = ((rtk >> c) & 1u) == 0u;
            const float cv = s_ex[c];
            if (avail && cv > best) { best = cv; bi = c; }
        }
        top_val[k] = best;
        top_idx[k] = (int)(s_top[bi] & 0x7FFu);
        rtk |= 1u << bi;
    }

    // ---- softmax over exact top-6 ----
    const float mx = top_val[0];
    float e[TOPK];
    float esum = 0.0f;
    #pragma unroll
    for (int k = 0; k < TOPK; ++k) { e[k] = __expf(top_val[k] - mx); esum += e[k]; }
    const float inv = 1.0f / esum;

    float outv = micro[(size_t)n * CHN + t];
    #pragma unroll
    for (int k = 0; k < TOPK; ++k)
        outv += (e[k] * inv) * micro_all[(size_t)top_idx[k] * CHN + t];
    out[n * CHN + t] = outv;

    // ---- fused loss: one device-scope atomic per block onto the 1e-4 seed ----
    if (t == 0) {
        const float lab = label[n];
        float l = 0.0f;
        #pragma unroll
        for (int k = 0; k < TOPK; ++k)
            l += (e[k] * inv) * fabsf(label_all[top_idx[k]] - lab);
        atomicAdd(out + N_Q * CHN, l * (1.0f / (float)N_Q));
    }
}

extern "C" void kernel_launch(void* const* d_in, const int* in_sizes, int n_in,
                              void* d_out, int out_size, void* d_ws, size_t ws_size,
                              hipStream_t stream) {
    const float* micro     = (const float*)d_in[0];
    const float* label     = (const float*)d_in[1];
    const float* micro_all = (const float*)d_in[2];
    const float* label_all = (const float*)d_in[3];
    const float* fc_w      = (const float*)d_in[4];
    float* out    = (float*)d_out;
    float* ws     = (float*)d_ws;
    float* logits = ws + WS_LOGIT_F;

    gcn_gemm<<<dim3(M_ALL / BM, N_Q / BN), 256, 0, stream>>>(
        micro_all, micro, fc_w, logits, out);
    gcn_topk<<<N_Q, BLOCK, 0, stream>>>(logits, micro, label, micro_all,
                                        label_all, fc_w, out);
}

// Round 6
// 81.960 us; speedup vs baseline: 1.5187x; 1.1131x over previous
//
#include <hip/hip_runtime.h>
#include <hip/hip_bf16.h>
#include <math.h>

#define N_Q   512
#define M_ALL 2048
#define CHN   256
#define TOPK  6
#define INV_C (1.0f / 256.0f)

// ws layout (float offsets): [4096..) logits [N][M]
#define WS_LOGIT 4096

typedef __bf16 bf16x8 __attribute__((ext_vector_type(8)));
typedef float  f32x4  __attribute__((ext_vector_type(4)));

static __device__ __forceinline__ unsigned short bfbits(float x) {
    __bf16 h = (__bf16)x;
    unsigned short u;
    __builtin_memcpy(&u, &h, 2);
    return u;
}

// =============== kernel 1: fused bias + MFMA-bf16 GEMM (approx logits) ===============
// R0-verified structure: coalesced fp32 stage -> LDS (bf16) -> ds_read fragments.
#define BM 64
#define BN 32
#define LDK 264   // 256 + 8 bf16 pad

__global__ __launch_bounds__(256) void gcn_gemm(
    const float* __restrict__ micro_all,  // A [M, C]
    const float* __restrict__ micro,      // B [N, C]
    const float* __restrict__ fc_w,
    float* __restrict__ logits,           // [N_Q][M_ALL]
    float* __restrict__ out)              // seeds loss accumulator
{
    __shared__ unsigned short sA[BM][LDK];
    __shared__ unsigned short sB[BN][LDK];
    __shared__ float s_bias[BM];

    const int t    = threadIdx.x;
    const int w    = t >> 6;
    const int l15  = t & 15;
    const int quad = (t >> 4) & 3;
    const int m0   = blockIdx.x * BM;
    const int n0   = blockIdx.y * BN;

    if (m0 == 0 && n0 == 0 && t == 0) out[N_Q * CHN] = 1e-4f;  // loss seed

    const int rg = t >> 4;
    const int c0 = (t & 15) * 4;

    float4 wv[4];
    #pragma unroll
    for (int cc = 0; cc < 4; ++cc) {
        float4 x = *(const float4*)(fc_w + c0 + cc * 64);
        x.x -= INV_C; x.y -= INV_C; x.z -= INV_C; x.w -= INV_C;
        wv[cc] = x;
    }

    #pragma unroll
    for (int i = 0; i < 4; ++i) {
        const int r = i * 16 + rg;
        const float* rp = micro_all + (size_t)(m0 + r) * CHN;
        float p = 0.0f;
        #pragma unroll
        for (int cc = 0; cc < 4; ++cc) {
            const float4 v = *(const float4*)(rp + c0 + cc * 64);
            const float sx = v.x * wv[cc].x;
            const float sy = v.y * wv[cc].y;
            const float sz = v.z * wv[cc].z;
            const float sw = v.w * wv[cc].w;
            ushort4 pk;
            pk.x = bfbits(sx); pk.y = bfbits(sy); pk.z = bfbits(sz); pk.w = bfbits(sw);
            *(ushort4*)&sA[r][c0 + cc * 64] = pk;
            p += v.x * sx + v.y * sy + v.z * sz + v.w * sw;
        }
        #pragma unroll
        for (int mask = 8; mask >= 1; mask >>= 1)
            p += __shfl_xor(p, mask, 64);
        if ((t & 15) == 0) s_bias[r] = p;
    }

    #pragma unroll
    for (int i = 0; i < 2; ++i) {
        const int r = i * 16 + rg;
        const float* rp = micro + (size_t)(n0 + r) * CHN;
        #pragma unroll
        for (int cc = 0; cc < 4; ++cc) {
            const float4 v = *(const float4*)(rp + c0 + cc * 64);
            ushort4 pk;
            pk.x = bfbits(v.x); pk.y = bfbits(v.y); pk.z = bfbits(v.z); pk.w = bfbits(v.w);
            *(ushort4*)&sB[r][c0 + cc * 64] = pk;
        }
    }
    __syncthreads();

    const int nt    = w & 1;
    const int mtp   = w >> 1;
    const int rowB  = nt * 16 + l15;
    const int rowA0 = mtp * 32 + l15;
    const int rowA1 = mtp * 32 + 16 + l15;

    f32x4 acc0 = {0.f, 0.f, 0.f, 0.f};
    f32x4 acc1 = {0.f, 0.f, 0.f, 0.f};
    #pragma unroll
    for (int ks = 0; ks < 8; ++ks) {
        const int k0 = ks * 32 + quad * 8;
        const bf16x8 a  = *(const bf16x8*)&sB[rowB][k0];
        const bf16x8 b0 = *(const bf16x8*)&sA[rowA0][k0];
        const bf16x8 b1 = *(const bf16x8*)&sA[rowA1][k0];
        acc0 = __builtin_amdgcn_mfma_f32_16x16x32_bf16(a, b0, acc0, 0, 0, 0);
        acc1 = __builtin_amdgcn_mfma_f32_16x16x32_bf16(a, b1, acc1, 0, 0, 0);
    }

    const float bias0 = s_bias[mtp * 32 + l15];
    const float bias1 = s_bias[mtp * 32 + 16 + l15];
    #pragma unroll
    for (int reg = 0; reg < 4; ++reg) {
        const int n = n0 + nt * 16 + quad * 4 + reg;
        logits[(size_t)n * M_ALL + m0 + mtp * 32 + l15]      = bias0 - 2.f * acc0[reg];
        logits[(size_t)n * M_ALL + m0 + mtp * 32 + 16 + l15] = bias1 - 2.f * acc1[reg];
    }
}

// =============== kernel 2: packed-key top-k + exact refine + fused loss ===============
#define BLOCK 256
#define WAVES (BLOCK / 64)
#define MPT   (M_ALL / BLOCK)
#define WTOP  8                   // per-wave exhaustive top-8 (packed keys)
#define NCAND (WAVES * WTOP)      // 32
#define NREF  10                  // exact-refined candidates

// sortable u32 key with 11-bit m-index embedded in the low (dropped) mantissa bits
static __device__ __forceinline__ unsigned key_of(float f, int m) {
    unsigned u = __float_as_uint(f);
    u = (u & 0x80000000u) ? ~u : (u | 0x80000000u);
    return (u & 0xFFFFF800u) | (unsigned)m;
}

__global__ __launch_bounds__(BLOCK) void gcn_topk(
    const float* __restrict__ logits,
    const float* __restrict__ micro,
    const float* __restrict__ label,
    const float* __restrict__ micro_all,
    const float* __restrict__ label_all,
    const float* __restrict__ fc_w,
    float* __restrict__ out)
{
    __shared__ unsigned s_keys[NCAND];
    __shared__ unsigned s_top[NREF];
    __shared__ float    s_ex[NREF];

    const int n    = blockIdx.x;
    const int t    = threadIdx.x;
    const int wave = t >> 6;
    const int lane = t & 63;

    // per-lane channel slice for the exact recompute (independent of logits)
    const float4 b4 = *(const float4*)(micro + (size_t)n * CHN + lane * 4);
    float4 w4 = *(const float4*)(fc_w + lane * 4);
    w4.x -= INV_C; w4.y -= INV_C; w4.z -= INV_C; w4.w -= INV_C;

    // load + pack 8 logits (m = t + j*256 fits 11 bits)
    unsigned k8[MPT];
    #pragma unroll
    for (int j = 0; j < MPT; ++j) {
        const int m = t + j * BLOCK;
        k8[j] = key_of(logits[(size_t)n * M_ALL + m], m);
    }

    // ---- per-wave exhaustive top-8 via packed umax butterflies ----
    #pragma unroll
    for (int k = 0; k < WTOP; ++k) {
        unsigned best = k8[0];
        #pragma unroll
        for (int j = 1; j < MPT; ++j) best = (k8[j] > best) ? k8[j] : best;
        #pragma unroll
        for (int mask = 32; mask > 0; mask >>= 1) {
            const unsigned ov = __shfl_xor(best, mask, 64);
            best = (ov > best) ? ov : best;
        }
        if (lane == 0) s_keys[wave * WTOP + k] = best;
        #pragma unroll
        for (int j = 0; j < MPT; ++j)
            k8[j] = (k8[j] == best) ? 0u : k8[j];
    }
    __syncthreads();

    // ---- top-10 of the 32 candidates: 32-lane bitonic sort (descending) ----
    {
        unsigned v = s_keys[lane & 31];
        #pragma unroll
        for (int k = 2; k <= 32; k <<= 1) {
            #pragma unroll
            for (int j = k >> 1; j >= 1; j >>= 1) {
                const unsigned pv = __shfl_xor(v, j, 64);
                const unsigned mx = (v > pv) ? v : pv;
                const unsigned mn = (v > pv) ? pv : v;
                const bool up    = ((lane & k) == 0);
                const bool lower = ((lane & j) == 0);
                v = (up == lower) ? mx : mn;   // descending in "up" blocks
            }
        }
        if (wave == 0 && lane < NREF) s_top[lane] = v;  // lanes 0..9 descending
    }
    __syncthreads();

    // ---- exact fp32 recompute of the 10 candidates ----
    for (int c = wave; c < NREF; c += WAVES) {
        const int m = (int)(s_top[c] & 0x7FFu);
        const float4 a = *(const float4*)(micro_all + (size_t)m * CHN + lane * 4);
        const float dx = a.x - b4.x;
        const float dy = a.y - b4.y;
        const float dz = a.z - b4.z;
        const float dw = a.w - b4.w;
        float acc = dx * dx * w4.x + dy * dy * w4.y + dz * dz * w4.z + dw * dw * w4.w;
        #pragma unroll
        for (int mask = 32; mask >= 1; mask >>= 1)
            acc += __shfl_xor(acc, mask, 64);
        if (lane == 0) s_ex[c] = acc;
    }
    __syncthreads();

    // ---- exact top-6 of 10 (fp32, index-tracked, every thread identical) ----
    float top_val[TOPK];
    int   top_idx[TOPK];
    unsigned rtk = 0u;
    #pragma unroll
    for (int k = 0; k < TOPK; ++k) {
        float best = -INFINITY;
        int   bi   = 0;
        #pragma unroll
        for (int c = 0; c < NREF; ++c) {
            const bool avail = ((rtk >> c) & 1u) == 0u;
            const float cv = s_ex[c];
            if (avail && cv > best) { best = cv; bi = c; }
        }
        top_val[k] = best;
        top_idx[k] = (int)(s_top[bi] & 0x7FFu);
        rtk |= 1u << bi;
    }

    // ---- softmax over exact top-6 ----
    const float mx = top_val[0];
    float e[TOPK];
    float esum = 0.0f;
    #pragma unroll
    for (int k = 0; k < TOPK; ++k) { e[k] = __expf(top_val[k] - mx); esum += e[k]; }
    const float inv = 1.0f / esum;

    float outv = micro[(size_t)n * CHN + t];
    #pragma unroll
    for (int k = 0; k < TOPK; ++k)
        outv += (e[k] * inv) * micro_all[(size_t)top_idx[k] * CHN + t];
    out[n * CHN + t] = outv;

    // ---- fused loss: one device-scope atomic per block onto the 1e-4 seed ----
    if (t == 0) {
        const float lab = label[n];
        float l = 0.0f;
        #pragma unroll
        for (int k = 0; k < TOPK; ++k)
            l += (e[k] * inv) * fabsf(label_all[top_idx[k]] - lab);
        atomicAdd(out + N_Q * CHN, l * (1.0f / (float)N_Q));
    }
}

extern "C" void kernel_launch(void* const* d_in, const int* in_sizes, int n_in,
                              void* d_out, int out_size, void* d_ws, size_t ws_size,
                              hipStream_t stream) {
    const float* micro     = (const float*)d_in[0];
    const float* label     = (const float*)d_in[1];
    const float* micro_all = (const float*)d_in[2];
    const float* label_all = (const float*)d_in[3];
    const float* fc_w      = (const float*)d_in[4];
    float* out    = (float*)d_out;
    float* ws     = (float*)d_ws;
    float* logits = ws + WS_LOGIT;

    gcn_gemm<<<dim3(M_ALL / BM, N_Q / BN), 256, 0, stream>>>(
        micro_all, micro, fc_w, logits, out);
    gcn_topk<<<N_Q, BLOCK, 0, stream>>>(logits, micro, label, micro_all,
                                        label_all, fc_w, out);
}

// Round 7
// 78.949 us; speedup vs baseline: 1.5766x; 1.0381x over previous
//
#include <hip/hip_runtime.h>
#include <hip/hip_bf16.h>
#include <math.h>

#define N_Q   512
#define M_ALL 2048
#define CHN   256
#define TOPK  6
#define INV_C (1.0f / 256.0f)

// ws layout (float offsets): [64..576) per-n loss, [4096..) logits [N][M]
#define WS_LOSS  64
#define WS_LOGIT 4096

typedef __bf16 bf16x8 __attribute__((ext_vector_type(8)));
typedef float  f32x4  __attribute__((ext_vector_type(4)));

static __device__ __forceinline__ unsigned short bfbits(float x) {
    __bf16 h = (__bf16)x;
    unsigned short u;
    __builtin_memcpy(&u, &h, 2);
    return u;
}

// =============== kernel 1: fused bias + MFMA-bf16 GEMM (approx logits) ===============
#define BM 64
#define BN 32
#define LDK 264   // 256 + 8 bf16 pad

__global__ __launch_bounds__(256) void gcn_gemm(
    const float* __restrict__ micro_all,  // A [M, C]
    const float* __restrict__ micro,      // B [N, C]
    const float* __restrict__ fc_w,
    float* __restrict__ logits)           // [N_Q][M_ALL]
{
    __shared__ unsigned short sA[BM][LDK];
    __shared__ unsigned short sB[BN][LDK];
    __shared__ float s_bias[BM];

    const int t    = threadIdx.x;
    const int w    = t >> 6;
    const int l15  = t & 15;
    const int quad = (t >> 4) & 3;
    const int m0   = blockIdx.x * BM;
    const int n0   = blockIdx.y * BN;

    const int rg = t >> 4;
    const int c0 = (t & 15) * 4;

    float4 wv[4];
    #pragma unroll
    for (int cc = 0; cc < 4; ++cc) {
        float4 x = *(const float4*)(fc_w + c0 + cc * 64);
        x.x -= INV_C; x.y -= INV_C; x.z -= INV_C; x.w -= INV_C;
        wv[cc] = x;
    }

    #pragma unroll
    for (int i = 0; i < 4; ++i) {
        const int r = i * 16 + rg;
        const float* rp = micro_all + (size_t)(m0 + r) * CHN;
        float p = 0.0f;
        #pragma unroll
        for (int cc = 0; cc < 4; ++cc) {
            const float4 v = *(const float4*)(rp + c0 + cc * 64);
            const float sx = v.x * wv[cc].x;
            const float sy = v.y * wv[cc].y;
            const float sz = v.z * wv[cc].z;
            const float sw = v.w * wv[cc].w;
            ushort4 pk;
            pk.x = bfbits(sx); pk.y = bfbits(sy); pk.z = bfbits(sz); pk.w = bfbits(sw);
            *(ushort4*)&sA[r][c0 + cc * 64] = pk;
            p += v.x * sx + v.y * sy + v.z * sz + v.w * sw;
        }
        #pragma unroll
        for (int mask = 8; mask >= 1; mask >>= 1)
            p += __shfl_xor(p, mask, 64);
        if ((t & 15) == 0) s_bias[r] = p;
    }

    #pragma unroll
    for (int i = 0; i < 2; ++i) {
        const int r = i * 16 + rg;
        const float* rp = micro + (size_t)(n0 + r) * CHN;
        #pragma unroll
        for (int cc = 0; cc < 4; ++cc) {
            const float4 v = *(const float4*)(rp + c0 + cc * 64);
            ushort4 pk;
            pk.x = bfbits(v.x); pk.y = bfbits(v.y); pk.z = bfbits(v.z); pk.w = bfbits(v.w);
            *(ushort4*)&sB[r][c0 + cc * 64] = pk;
        }
    }
    __syncthreads();

    const int nt    = w & 1;
    const int mtp   = w >> 1;
    const int rowB  = nt * 16 + l15;
    const int rowA0 = mtp * 32 + l15;
    const int rowA1 = mtp * 32 + 16 + l15;

    f32x4 acc0 = {0.f, 0.f, 0.f, 0.f};
    f32x4 acc1 = {0.f, 0.f, 0.f, 0.f};
    #pragma unroll
    for (int ks = 0; ks < 8; ++ks) {
        const int k0 = ks * 32 + quad * 8;
        const bf16x8 a  = *(const bf16x8*)&sB[rowB][k0];
        const bf16x8 b0 = *(const bf16x8*)&sA[rowA0][k0];
        const bf16x8 b1 = *(const bf16x8*)&sA[rowA1][k0];
        acc0 = __builtin_amdgcn_mfma_f32_16x16x32_bf16(a, b0, acc0, 0, 0, 0);
        acc1 = __builtin_amdgcn_mfma_f32_16x16x32_bf16(a, b1, acc1, 0, 0, 0);
    }

    const float bias0 = s_bias[mtp * 32 + l15];
    const float bias1 = s_bias[mtp * 32 + 16 + l15];
    #pragma unroll
    for (int reg = 0; reg < 4; ++reg) {
        const int n = n0 + nt * 16 + quad * 4 + reg;
        logits[(size_t)n * M_ALL + m0 + mtp * 32 + l15]      = bias0 - 2.f * acc0[reg];
        logits[(size_t)n * M_ALL + m0 + mtp * 32 + 16 + l15] = bias1 - 2.f * acc1[reg];
    }
}

// =============== kernel 2: packed-key top-k + exact refine + epilogue ===============
#define BLOCK 256
#define WAVES (BLOCK / 64)
#define MPT   (M_ALL / BLOCK)
#define WTOP  8                   // per-wave exhaustive top-8 (packed keys)
#define NCAND (WAVES * WTOP)      // 32
#define NREF  10                  // exact-refined candidates

// sortable u32 key with 11-bit m-index embedded in the low (dropped) mantissa bits
static __device__ __forceinline__ unsigned key_of(float f, int m) {
    unsigned u = __float_as_uint(f);
    u = (u & 0x80000000u) ? ~u : (u | 0x80000000u);
    return (u & 0xFFFFF800u) | (unsigned)m;
}

__global__ __launch_bounds__(BLOCK) void gcn_topk(
    const float* __restrict__ logits,
    const float* __restrict__ micro,
    const float* __restrict__ label,
    const float* __restrict__ micro_all,
    const float* __restrict__ label_all,
    const float* __restrict__ fc_w,
    float* __restrict__ out,
    float* __restrict__ loss_arr)
{
    __shared__ unsigned s_keys[NCAND];
    __shared__ unsigned s_top[NREF];
    __shared__ float    s_ex[NREF];

    const int n    = blockIdx.x;
    const int t    = threadIdx.x;
    const int wave = t >> 6;
    const int lane = t & 63;

    // per-lane channel slice for the exact recompute (independent of logits)
    const float4 b4 = *(const float4*)(micro + (size_t)n * CHN + lane * 4);
    float4 w4 = *(const float4*)(fc_w + lane * 4);
    w4.x -= INV_C; w4.y -= INV_C; w4.z -= INV_C; w4.w -= INV_C;

    // load + pack 8 logits (m = t + j*256 fits 11 bits)
    unsigned k8[MPT];
    #pragma unroll
    for (int j = 0; j < MPT; ++j) {
        const int m = t + j * BLOCK;
        k8[j] = key_of(logits[(size_t)n * M_ALL + m], m);
    }

    // ---- per-wave exhaustive top-8 via packed umax butterflies ----
    #pragma unroll
    for (int k = 0; k < WTOP; ++k) {
        unsigned best = k8[0];
        #pragma unroll
        for (int j = 1; j < MPT; ++j) best = (k8[j] > best) ? k8[j] : best;
        #pragma unroll
        for (int mask = 32; mask > 0; mask >>= 1) {
            const unsigned ov = __shfl_xor(best, mask, 64);
            best = (ov > best) ? ov : best;
        }
        if (lane == 0) s_keys[wave * WTOP + k] = best;
        #pragma unroll
        for (int j = 0; j < MPT; ++j)
            k8[j] = (k8[j] == best) ? 0u : k8[j];
    }
    __syncthreads();

    // ---- top-10 of the 32 candidates: 32-lane bitonic sort (descending) ----
    {
        unsigned v = s_keys[lane & 31];
        #pragma unroll
        for (int k = 2; k <= 32; k <<= 1) {
            #pragma unroll
            for (int j = k >> 1; j >= 1; j >>= 1) {
                const unsigned pv = __shfl_xor(v, j, 64);
                const unsigned mx = (v > pv) ? v : pv;
                const unsigned mn = (v > pv) ? pv : v;
                const bool up    = ((lane & k) == 0);
                const bool lower = ((lane & j) == 0);
                v = (up == lower) ? mx : mn;   // descending in "up" blocks
            }
        }
        if (wave == 0 && lane < NREF) s_top[lane] = v;  // lanes 0..9 descending
    }
    __syncthreads();

    // ---- exact fp32 recompute of the 10 candidates ----
    for (int c = wave; c < NREF; c += WAVES) {
        const int m = (int)(s_top[c] & 0x7FFu);
        const float4 a = *(const float4*)(micro_all + (size_t)m * CHN + lane * 4);
        const float dx = a.x - b4.x;
        const float dy = a.y - b4.y;
        const float dz = a.z - b4.z;
        const float dw = a.w - b4.w;
        float acc = dx * dx * w4.x + dy * dy * w4.y + dz * dz * w4.z + dw * dw * w4.w;
        #pragma unroll
        for (int mask = 32; mask >= 1; mask >>= 1)
            acc += __shfl_xor(acc, mask, 64);
        if (lane == 0) s_ex[c] = acc;
    }
    __syncthreads();

    // ---- exact top-6 of 10 (fp32, index-tracked, every thread identical) ----
    float top_val[TOPK];
    int   top_idx[TOPK];
    unsigned rtk = 0u;
    #pragma unroll
    for (int k = 0; k < TOPK; ++k) {
        float best = -INFINITY;
        int   bi   = 0;
        #pragma unroll
        for (int c = 0; c < NREF; ++c) {
            const bool avail = ((rtk >> c) & 1u) == 0u;
            const float cv = s_ex[c];
            if (avail && cv > best) { best = cv; bi = c; }
        }
        top_val[k] = best;
        top_idx[k] = (int)(s_top[bi] & 0x7FFu);
        rtk |= 1u << bi;
    }

    // ---- softmax over exact top-6 ----
    const float mx = top_val[0];
    float e[TOPK];
    float esum = 0.0f;
    #pragma unroll
    for (int k = 0; k < TOPK; ++k) { e[k] = __expf(top_val[k] - mx); esum += e[k]; }
    const float inv = 1.0f / esum;

    float outv = micro[(size_t)n * CHN + t];
    #pragma unroll
    for (int k = 0; k < TOPK; ++k)
        outv += (e[k] * inv) * micro_all[(size_t)top_idx[k] * CHN + t];
    out[n * CHN + t] = outv;

    if (t == 0) {
        const float lab = label[n];
        float l = 0.0f;
        #pragma unroll
        for (int k = 0; k < TOPK; ++k)
            l += (e[k] * inv) * fabsf(label_all[top_idx[k]] - lab);
        loss_arr[n] = l;
    }
}

// =============== kernel 3: reduce 512 per-n losses ===============
__global__ __launch_bounds__(256) void gcn_finalize(
    const float* __restrict__ loss_arr,
    float* __restrict__ out)
{
    __shared__ float red[4];
    const int t = threadIdx.x;
    float v = loss_arr[t] + loss_arr[t + 256];
    #pragma unroll
    for (int mask = 32; mask >= 1; mask >>= 1)
        v += __shfl_xor(v, mask, 64);
    if ((t & 63) == 0) red[t >> 6] = v;
    __syncthreads();
    if (t == 0)
        out[N_Q * CHN] = 1e-4f + (red[0] + red[1] + red[2] + red[3]) / (float)N_Q;
}

extern "C" void kernel_launch(void* const* d_in, const int* in_sizes, int n_in,
                              void* d_out, int out_size, void* d_ws, size_t ws_size,
                              hipStream_t stream) {
    const float* micro     = (const float*)d_in[0];
    const float* label     = (const float*)d_in[1];
    const float* micro_all = (const float*)d_in[2];
    const float* label_all = (const float*)d_in[3];
    const float* fc_w      = (const float*)d_in[4];
    float* out    = (float*)d_out;
    float* ws     = (float*)d_ws;
    float* loss   = ws + WS_LOSS;
    float* logits = ws + WS_LOGIT;

    gcn_gemm<<<dim3(M_ALL / BM, N_Q / BN), 256, 0, stream>>>(
        micro_all, micro, fc_w, logits);
    gcn_topk<<<N_Q, BLOCK, 0, stream>>>(logits, micro, label, micro_all,
                                        label_all, fc_w, out, loss);
    gcn_finalize<<<1, 256, 0, stream>>>(loss, out);
}